// Round 1
// baseline (582.279 us; speedup 1.0000x reference)
//
#include <hip/hip_runtime.h>
#include <math.h>

#define N_NODES 100000

// ---------------- helpers ----------------
static inline size_t align_up(size_t x, size_t a){ return (x + a - 1) & ~(a - 1); }

// Detect whether edge_index arrived as int64 (odd int32 words all zero) or int32.
__global__ void k_detect(const int* __restrict__ ei, int* __restrict__ flag){
  if(blockIdx.x==0 && threadIdx.x==0){
    int is64 = 1;
    for(int k=0;k<64;k++){ if(ei[2*k+1] != 0){ is64 = 0; break; } }
    *flag = is64;
  }
}

__global__ void k_convert(const int* __restrict__ ei, const int* __restrict__ flag,
                          int* __restrict__ src32, int* __restrict__ dst32, int E){
  int is64 = *flag;
  int stride = gridDim.x * blockDim.x;
  for(int e = blockIdx.x*blockDim.x + threadIdx.x; e < E; e += stride){
    if(is64){ src32[e] = ei[2*e]; dst32[e] = ei[2*(E + e)]; }
    else    { src32[e] = ei[e];   dst32[e] = ei[E + e]; }
  }
}

__global__ void k_zero(int* __restrict__ p, int n){
  int i = blockIdx.x*blockDim.x + threadIdx.x;
  if(i < n) p[i] = 0;
}

__global__ void k_count(const int* __restrict__ dst32, int* __restrict__ cnt, int E){
  int stride = gridDim.x * blockDim.x;
  for(int e = blockIdx.x*blockDim.x + threadIdx.x; e < E; e += stride)
    atomicAdd(&cnt[dst32[e]], 1);
}

// ---------------- scan (3-phase) ----------------
// chunk = 1024 elements per block; block = 256 threads * 4 elements.
__global__ void k_scan_part(const int* __restrict__ cnt, int* __restrict__ bsum, int n){
  __shared__ int red[256];
  int b = blockIdx.x, t = threadIdx.x;
  int base = b*1024 + t*4;
  int s = 0;
  #pragma unroll
  for(int k=0;k<4;k++){ int i = base + k; if(i < n) s += cnt[i]; }
  red[t] = s; __syncthreads();
  for(int off=128; off>0; off>>=1){
    if(t < off) red[t] += red[t+off];
    __syncthreads();
  }
  if(t==0) bsum[b] = red[0];
}

__global__ void k_scan_top(int* __restrict__ bsum, int nb){
  __shared__ int sh[128];
  int t = threadIdx.x;
  int v = (t < nb) ? bsum[t] : 0;
  sh[t] = v; __syncthreads();
  int inc = v;
  for(int off=1; off<128; off<<=1){
    int add = (t >= off) ? sh[t-off] : 0;
    __syncthreads();
    inc += add; sh[t] = inc;
    __syncthreads();
  }
  if(t < nb) bsum[t] = inc - v;   // exclusive
}

__global__ void k_scan_down(const int* __restrict__ cnt, const int* __restrict__ bsum,
                            int* __restrict__ offs, int* __restrict__ cursor,
                            float* __restrict__ dinv, int n, int E){
  __shared__ int sh[256];
  int b = blockIdx.x, t = threadIdx.x;
  int base = b*1024 + t*4;
  int c[4]; int local = 0;
  #pragma unroll
  for(int k=0;k<4;k++){ int i = base + k; c[k] = (i < n) ? cnt[i] : 0; local += c[k]; }
  sh[t] = local; __syncthreads();
  int inc = local;
  for(int off=1; off<256; off<<=1){
    int add = (t >= off) ? sh[t-off] : 0;
    __syncthreads();
    inc += add; sh[t] = inc;
    __syncthreads();
  }
  int running = bsum[b] + (inc - local);
  #pragma unroll
  for(int k=0;k<4;k++){
    int i = base + k;
    if(i < n){
      offs[i] = running;
      cursor[i] = running;
      dinv[i] = rsqrtf((float)(c[k] + 1));   // deg includes the self-loop
      running += c[k];
    }
  }
  if(b==0 && t==0) offs[n] = E;
}

__global__ void k_fill(const int* __restrict__ src32, const int* __restrict__ dst32,
                       int* __restrict__ cursor, int* __restrict__ csr, int E){
  int stride = gridDim.x * blockDim.x;
  for(int e = blockIdx.x*blockDim.x + threadIdx.x; e < E; e += stride){
    int d = dst32[e];
    int pos = atomicAdd(&cursor[d], 1);
    csr[pos] = src32[e];
  }
}

// ---------------- GEMM: h = x @ W1  (fp32 vector; no fp32 MFMA on CDNA4) --------
__global__ void k_pad_w1(const float* __restrict__ w1, float* __restrict__ w1p){
  int i = blockIdx.x*blockDim.x + threadIdx.x;
  if(i < 168*128) w1p[i] = (i < 165*128) ? w1[i] : 0.f;
}

// block = 256 threads = 64 col-lanes x 4 row-groups; 64 rows per block.
__global__ __launch_bounds__(256) void k_gemm(const float* __restrict__ x,
                                              const float* __restrict__ w1p,
                                              float* __restrict__ h, int n){
  __shared__ float xs[64][168];   // 43008 B
  int t = threadIdx.x;
  int lane = t & 63;
  int grp  = t >> 6;              // 0..3
  int rowbase = blockIdx.x * 64;

  // cooperative load: each group loads its 16 rows (cols lane, lane+64, lane+128)
  for(int r = grp*16; r < grp*16 + 16; ++r){
    int grow = rowbase + r;
    bool valid = grow < n;
    const float* xr = x + (size_t)grow * 165;
    float v0 = valid ? xr[lane]      : 0.f;
    float v1 = valid ? xr[lane + 64] : 0.f;
    float v2 = (valid && lane + 128 < 165) ? xr[lane + 128] : 0.f;
    xs[r][lane]      = v0;
    xs[r][lane + 64] = v1;
    if(lane + 128 < 168) xs[r][lane + 128] = v2;   // zero-pads k=165..167
  }
  __syncthreads();

  float acc0[16], acc1[16];
  #pragma unroll
  for(int r=0;r<16;r++){ acc0[r]=0.f; acc1[r]=0.f; }
  int j0 = lane, j1 = lane + 64;

  for(int kq = 0; kq < 42; ++kq){
    int k4 = kq * 4;
    float w00 = w1p[(k4+0)*128 + j0];
    float w01 = w1p[(k4+1)*128 + j0];
    float w02 = w1p[(k4+2)*128 + j0];
    float w03 = w1p[(k4+3)*128 + j0];
    float w10 = w1p[(k4+0)*128 + j1];
    float w11 = w1p[(k4+1)*128 + j1];
    float w12 = w1p[(k4+2)*128 + j1];
    float w13 = w1p[(k4+3)*128 + j1];
    #pragma unroll
    for(int r=0;r<16;r++){
      float4 xv = *(const float4*)&xs[grp*16 + r][k4];
      acc0[r] = fmaf(xv.w, w03, fmaf(xv.z, w02, fmaf(xv.y, w01, fmaf(xv.x, w00, acc0[r]))));
      acc1[r] = fmaf(xv.w, w13, fmaf(xv.z, w12, fmaf(xv.y, w11, fmaf(xv.x, w10, acc1[r]))));
    }
  }

  #pragma unroll
  for(int r=0;r<16;r++){
    int grow = rowbase + grp*16 + r;
    if(grow < n){
      h[(size_t)grow*128 + j0] = acc0[r];
      h[(size_t)grow*128 + j1] = acc1[r];
    }
  }
}

// ---------------- layer-1 aggregation + relu + dot(W4), fused ----------------
// one wave (64 lanes) per node, 2 features per lane (float2)
__global__ __launch_bounds__(256) void k_agg1(const float* __restrict__ h,
                                              const int* __restrict__ offs,
                                              const int* __restrict__ csr,
                                              const float* __restrict__ dinv,
                                              const float* __restrict__ b1,
                                              const float* __restrict__ w4,
                                              float* __restrict__ h2, int n){
  int wv = threadIdx.x >> 6;
  int lane = threadIdx.x & 63;
  int i = blockIdx.x * 4 + wv;
  if(i >= n) return;

  float di = dinv[i];
  int s0 = offs[i], s1 = offs[i+1];
  int f = lane * 2;

  float ax = 0.f, ay = 0.f;
  for(int e = s0; e < s1; ++e){
    int s = csr[e];
    float ds = dinv[s];
    float2 hv = *(const float2*)&h[(size_t)s*128 + f];
    ax = fmaf(ds, hv.x, ax);
    ay = fmaf(ds, hv.y, ay);
  }
  // scale by dinv[i] (factored out of the loop), then self-loop term di^2 * h[i]
  float2 hs = *(const float2*)&h[(size_t)i*128 + f];
  ax = di * ax + di*di*hs.x;
  ay = di * ay + di*di*hs.y;

  float2 bb = *(const float2*)&b1[f];
  float o0 = fmaxf(ax + bb.x, 0.f);
  float o1 = fmaxf(ay + bb.y, 0.f);

  float2 wv4 = *(const float2*)&w4[f];
  float p = o0*wv4.x + o1*wv4.y;
  #pragma unroll
  for(int offm=32; offm>0; offm>>=1) p += __shfl_xor(p, offm, 64);
  if(lane == 0) h2[i] = p;
}

// ---------------- layer-2 aggregation + sigmoid ----------------
__global__ void k_agg2(const float* __restrict__ h2, const int* __restrict__ offs,
                       const int* __restrict__ csr, const float* __restrict__ dinv,
                       const float* __restrict__ b4, float* __restrict__ out, int n){
  int i = blockIdx.x*blockDim.x + threadIdx.x;
  if(i >= n) return;
  float di = dinv[i];
  float z = 0.f;
  int s1 = offs[i+1];
  for(int e = offs[i]; e < s1; ++e){
    int s = csr[e];
    z = fmaf(dinv[s], h2[s], z);
  }
  z = di*z + di*di*h2[i] + b4[0];
  out[i] = 1.f / (1.f + expf(-z));
}

// ---------------- launch ----------------
extern "C" void kernel_launch(void* const* d_in, const int* in_sizes, int n_in,
                              void* d_out, int out_size, void* d_ws, size_t ws_size,
                              hipStream_t stream){
  const float* x  = (const float*)d_in[0];
  const int*   ei = (const int*)d_in[1];
  const float* w1 = (const float*)d_in[2];
  const float* b1 = (const float*)d_in[3];
  const float* w4 = (const float*)d_in[4];
  const float* b4 = (const float*)d_in[5];
  float* out = (float*)d_out;

  const int n = N_NODES;
  const int E = in_sizes[1] / 2;

  char* ws = (char*)d_ws;
  size_t off = 0;
  auto carve = [&](size_t bytes)->void*{
    void* p = ws + off; off = align_up(off + bytes, 256); return p;
  };
  int*   flag   = (int*)carve(4);
  int*   cnt    = (int*)carve((size_t)n*4);
  int*   offs   = (int*)carve((size_t)(n+1)*4);
  int*   cursor = (int*)carve((size_t)n*4);
  int*   bsum   = (int*)carve(128*4);
  float* dinv   = (float*)carve((size_t)n*4);
  int*   src32  = (int*)carve((size_t)E*4);
  int*   dst32  = (int*)carve((size_t)E*4);
  int*   csr    = (int*)carve((size_t)E*4);
  float* w1p    = (float*)carve(168*128*4);
  float* h      = (float*)carve((size_t)n*128*4);
  float* h2     = (float*)carve((size_t)n*4);
  (void)ws_size;

  int nb = (n + 1023) / 1024;   // 98

  k_zero   <<<(n+255)/256, 256, 0, stream>>>(cnt, n);
  k_detect <<<1, 64, 0, stream>>>(ei, flag);
  k_convert<<<2048, 256, 0, stream>>>(ei, flag, src32, dst32, E);
  k_count  <<<2048, 256, 0, stream>>>(dst32, cnt, E);
  k_scan_part<<<nb, 256, 0, stream>>>(cnt, bsum, n);
  k_scan_top <<<1, 128, 0, stream>>>(bsum, nb);
  k_scan_down<<<nb, 256, 0, stream>>>(cnt, bsum, offs, cursor, dinv, n, E);
  k_fill   <<<2048, 256, 0, stream>>>(src32, dst32, cursor, csr, E);
  k_pad_w1 <<<84, 256, 0, stream>>>(w1, w1p);
  k_gemm   <<<(n+63)/64, 256, 0, stream>>>(x, w1p, h, n);
  k_agg1   <<<(n+3)/4, 256, 0, stream>>>(h, offs, csr, dinv, b1, w4, h2, n);
  k_agg2   <<<(n+255)/256, 256, 0, stream>>>(h2, offs, csr, dinv, b4, out, n);
}

// Round 2
// 576.108 us; speedup vs baseline: 1.0107x; 1.0107x over previous
//
#include <hip/hip_runtime.h>
#include <hip/hip_bf16.h>
#include <math.h>

#define N_NODES 100000

static inline size_t align_up(size_t x, size_t a){ return (x + a - 1) & ~(a - 1); }

__device__ __forceinline__ float bf_lo(unsigned u){ return __uint_as_float(u << 16); }
__device__ __forceinline__ float bf_hi(unsigned u){ return __uint_as_float(u & 0xffff0000u); }

// ---------------- zero ----------------
__global__ void k_zero(int* __restrict__ p, int n){
  int i = blockIdx.x*blockDim.x + threadIdx.x;
  if(i < n) p[i] = 0;
}

// ---------------- convert + count (int64/int32 detect inlined) ----------------
__global__ void k_convert_count(const int* __restrict__ ei,
                                int* __restrict__ src32, int* __restrict__ dst32,
                                int* __restrict__ cnt, int E){
  __shared__ int s_is64;
  if(threadIdx.x == 0){
    int is64 = 1;
    for(int k=0;k<64;k++){ if(ei[2*k+1] != 0){ is64 = 0; break; } }
    s_is64 = is64;
  }
  __syncthreads();
  int is64 = s_is64;
  int stride = gridDim.x * blockDim.x;
  for(int e = blockIdx.x*blockDim.x + threadIdx.x; e < E; e += stride){
    int s, d;
    if(is64){ s = ei[2*e]; d = ei[2*(E + e)]; }
    else    { s = ei[e];   d = ei[E + e]; }
    src32[e] = s; dst32[e] = d;
    atomicAdd(&cnt[d], 1);
  }
}

// ---------------- scan (3-phase) ----------------
__global__ void k_scan_part(const int* __restrict__ cnt, int* __restrict__ bsum, int n){
  __shared__ int red[256];
  int b = blockIdx.x, t = threadIdx.x;
  int base = b*1024 + t*4;
  int s = 0;
  #pragma unroll
  for(int k=0;k<4;k++){ int i = base + k; if(i < n) s += cnt[i]; }
  red[t] = s; __syncthreads();
  for(int off=128; off>0; off>>=1){
    if(t < off) red[t] += red[t+off];
    __syncthreads();
  }
  if(t==0) bsum[b] = red[0];
}

__global__ void k_scan_top(int* __restrict__ bsum, int nb){
  __shared__ int sh[128];
  int t = threadIdx.x;
  int v = (t < nb) ? bsum[t] : 0;
  sh[t] = v; __syncthreads();
  int inc = v;
  for(int off=1; off<128; off<<=1){
    int add = (t >= off) ? sh[t-off] : 0;
    __syncthreads();
    inc += add; sh[t] = inc;
    __syncthreads();
  }
  if(t < nb) bsum[t] = inc - v;   // exclusive
}

__global__ void k_scan_down(const int* __restrict__ cnt, const int* __restrict__ bsum,
                            int* __restrict__ offs, int* __restrict__ cursor,
                            float* __restrict__ dinv, int n, int E){
  __shared__ int sh[256];
  int b = blockIdx.x, t = threadIdx.x;
  int base = b*1024 + t*4;
  int c[4]; int local = 0;
  #pragma unroll
  for(int k=0;k<4;k++){ int i = base + k; c[k] = (i < n) ? cnt[i] : 0; local += c[k]; }
  sh[t] = local; __syncthreads();
  int inc = local;
  for(int off=1; off<256; off<<=1){
    int add = (t >= off) ? sh[t-off] : 0;
    __syncthreads();
    inc += add; sh[t] = inc;
    __syncthreads();
  }
  int running = bsum[b] + (inc - local);
  #pragma unroll
  for(int k=0;k<4;k++){
    int i = base + k;
    if(i < n){
      offs[i] = running;
      cursor[i] = running;
      dinv[i] = rsqrtf((float)(c[k] + 1));   // deg includes self-loop
      running += c[k];
    }
  }
  if(b==0 && t==0) offs[n] = E;
}

__global__ void k_fill(const int* __restrict__ src32, const int* __restrict__ dst32,
                       int* __restrict__ cursor, int* __restrict__ csr, int E){
  int stride = gridDim.x * blockDim.x;
  for(int e = blockIdx.x*blockDim.x + threadIdx.x; e < E; e += stride){
    int d = dst32[e];
    int pos = atomicAdd(&cursor[d], 1);
    csr[pos] = src32[e];
  }
}

// ---------------- GEMM: hsc = (x @ W1) * dinv[row], stored bf16 ----------------
__global__ void k_pad_w1(const float* __restrict__ w1, float* __restrict__ w1p){
  int i = blockIdx.x*blockDim.x + threadIdx.x;
  if(i < 168*128) w1p[i] = (i < 165*128) ? w1[i] : 0.f;
}

__global__ __launch_bounds__(256) void k_gemm(const float* __restrict__ x,
                                              const float* __restrict__ w1p,
                                              const float* __restrict__ dinv,
                                              __hip_bfloat16* __restrict__ hsc, int n){
  __shared__ float xs[64][168];   // 43008 B
  int t = threadIdx.x;
  int lane = t & 63;
  int grp  = t >> 6;              // 0..3
  int rowbase = blockIdx.x * 64;

  for(int r = grp*16; r < grp*16 + 16; ++r){
    int grow = rowbase + r;
    bool valid = grow < n;
    const float* xr = x + (size_t)grow * 165;
    float v0 = valid ? xr[lane]      : 0.f;
    float v1 = valid ? xr[lane + 64] : 0.f;
    float v2 = (valid && lane + 128 < 165) ? xr[lane + 128] : 0.f;
    xs[r][lane]      = v0;
    xs[r][lane + 64] = v1;
    if(lane + 128 < 168) xs[r][lane + 128] = v2;   // zero-pads k=165..167
  }
  __syncthreads();

  float acc0[16], acc1[16];
  #pragma unroll
  for(int r=0;r<16;r++){ acc0[r]=0.f; acc1[r]=0.f; }
  int j0 = lane, j1 = lane + 64;

  for(int kq = 0; kq < 42; ++kq){
    int k4 = kq * 4;
    float w00 = w1p[(k4+0)*128 + j0];
    float w01 = w1p[(k4+1)*128 + j0];
    float w02 = w1p[(k4+2)*128 + j0];
    float w03 = w1p[(k4+3)*128 + j0];
    float w10 = w1p[(k4+0)*128 + j1];
    float w11 = w1p[(k4+1)*128 + j1];
    float w12 = w1p[(k4+2)*128 + j1];
    float w13 = w1p[(k4+3)*128 + j1];
    #pragma unroll
    for(int r=0;r<16;r++){
      float4 xv = *(const float4*)&xs[grp*16 + r][k4];
      acc0[r] = fmaf(xv.w, w03, fmaf(xv.z, w02, fmaf(xv.y, w01, fmaf(xv.x, w00, acc0[r]))));
      acc1[r] = fmaf(xv.w, w13, fmaf(xv.z, w12, fmaf(xv.y, w11, fmaf(xv.x, w10, acc1[r]))));
    }
  }

  #pragma unroll
  for(int r=0;r<16;r++){
    int grow = rowbase + grp*16 + r;
    if(grow < n){
      float di = dinv[grow];
      hsc[(size_t)grow*128 + j0] = __float2bfloat16(di * acc0[r]);
      hsc[(size_t)grow*128 + j1] = __float2bfloat16(di * acc1[r]);
    }
  }
}

// ------- layer-1 aggregation + relu + dot(W4) fused; emits g = dinv*h2 -------
// one wave per node, 2 bf16 features per lane (one dword load per edge)
__global__ __launch_bounds__(256) void k_agg1(const __hip_bfloat16* __restrict__ hsc,
                                              const int* __restrict__ offs,
                                              const int* __restrict__ csr,
                                              const float* __restrict__ dinv,
                                              const float* __restrict__ b1,
                                              const float* __restrict__ w4,
                                              float* __restrict__ g, int n){
  int wv = threadIdx.x >> 6;
  int lane = threadIdx.x & 63;
  int i = blockIdx.x * 4 + wv;
  if(i >= n) return;

  float di = dinv[i];
  int s0 = offs[i], s1 = offs[i+1];
  int f = lane * 2;

  float ax = 0.f, ay = 0.f;
  int e = s0;
  for(; e + 1 < s1; e += 2){
    int sA = csr[e], sB = csr[e+1];
    unsigned uA = ((const unsigned*)(hsc + (size_t)sA*128))[lane];
    unsigned uB = ((const unsigned*)(hsc + (size_t)sB*128))[lane];
    ax += bf_lo(uA) + bf_lo(uB);
    ay += bf_hi(uA) + bf_hi(uB);
  }
  if(e < s1){
    int sA = csr[e];
    unsigned uA = ((const unsigned*)(hsc + (size_t)sA*128))[lane];
    ax += bf_lo(uA);
    ay += bf_hi(uA);
  }
  // self-loop: + hsc[i] (already dinv[i]-scaled), then scale sum by di
  unsigned uS = ((const unsigned*)(hsc + (size_t)i*128))[lane];
  ax = di * (ax + bf_lo(uS));
  ay = di * (ay + bf_hi(uS));

  float2 bb = *(const float2*)&b1[f];
  float o0 = fmaxf(ax + bb.x, 0.f);
  float o1 = fmaxf(ay + bb.y, 0.f);

  float2 wv4 = *(const float2*)&w4[f];
  float p = o0*wv4.x + o1*wv4.y;
  #pragma unroll
  for(int offm=32; offm>0; offm>>=1) p += __shfl_xor(p, offm, 64);
  if(lane == 0) g[i] = di * p;     // g = dinv * h2
}

// ---------------- layer-2 aggregation: edge-parallel atomics ----------------
__global__ void k_agg2e(const int* __restrict__ src32, const int* __restrict__ dst32,
                        const float* __restrict__ g, float* __restrict__ acc, int E){
  int stride = gridDim.x * blockDim.x;
  for(int e = blockIdx.x*blockDim.x + threadIdx.x; e < E; e += stride){
    atomicAdd(&acc[dst32[e]], g[src32[e]]);
  }
}

__global__ void k_final(const float* __restrict__ acc, const float* __restrict__ g,
                        const float* __restrict__ dinv, const float* __restrict__ b4,
                        float* __restrict__ out, int n){
  int i = blockIdx.x*blockDim.x + threadIdx.x;
  if(i >= n) return;
  float di = dinv[i];
  float z = di * (acc[i] + g[i]) + b4[0];   // di*(sum_nbr g + g_self) ; g=dinv*h2
  out[i] = 1.f / (1.f + expf(-z));
}

// ---------------- launch ----------------
extern "C" void kernel_launch(void* const* d_in, const int* in_sizes, int n_in,
                              void* d_out, int out_size, void* d_ws, size_t ws_size,
                              hipStream_t stream){
  const float* x  = (const float*)d_in[0];
  const int*   ei = (const int*)d_in[1];
  const float* w1 = (const float*)d_in[2];
  const float* b1 = (const float*)d_in[3];
  const float* w4 = (const float*)d_in[4];
  const float* b4 = (const float*)d_in[5];
  float* out = (float*)d_out;

  const int n = N_NODES;
  const int E = in_sizes[1] / 2;

  char* ws = (char*)d_ws;
  size_t off = 0;
  auto carve = [&](size_t bytes)->void*{
    void* p = ws + off; off = align_up(off + bytes, 256); return p;
  };
  int*   cntacc = (int*)carve((size_t)2*n*4);   // cnt[n] | acc[n] zeroed together
  int*   cnt    = cntacc;
  float* acc    = (float*)(cntacc + n);
  int*   offs   = (int*)carve((size_t)(n+1)*4);
  int*   cursor = (int*)carve((size_t)n*4);
  int*   bsum   = (int*)carve(128*4);
  float* dinv   = (float*)carve((size_t)n*4);
  int*   src32  = (int*)carve((size_t)E*4);
  int*   dst32  = (int*)carve((size_t)E*4);
  int*   csr    = (int*)carve((size_t)E*4);
  float* w1p    = (float*)carve(168*128*4);
  __hip_bfloat16* hsc = (__hip_bfloat16*)carve((size_t)n*128*2);
  float* g      = (float*)carve((size_t)n*4);
  (void)ws_size;

  int nb = (n + 1023) / 1024;   // 98

  k_zero         <<<(2*n+255)/256, 256, 0, stream>>>(cntacc, 2*n);
  k_convert_count<<<2048, 256, 0, stream>>>(ei, src32, dst32, cnt, E);
  k_scan_part    <<<nb, 256, 0, stream>>>(cnt, bsum, n);
  k_scan_top     <<<1, 128, 0, stream>>>(bsum, nb);
  k_scan_down    <<<nb, 256, 0, stream>>>(cnt, bsum, offs, cursor, dinv, n, E);
  k_fill         <<<2048, 256, 0, stream>>>(src32, dst32, cursor, csr, E);
  k_pad_w1       <<<84, 256, 0, stream>>>(w1, w1p);
  k_gemm         <<<(n+63)/64, 256, 0, stream>>>(x, w1p, dinv, hsc, n);
  k_agg1         <<<(n+3)/4, 256, 0, stream>>>(hsc, offs, csr, dinv, b1, w4, g, n);
  k_agg2e        <<<2048, 256, 0, stream>>>(src32, dst32, g, acc, E);
  k_final        <<<(n+255)/256, 256, 0, stream>>>(acc, g, dinv, b4, out, n);
}

// Round 3
// 380.536 us; speedup vs baseline: 1.5302x; 1.5139x over previous
//
#include <hip/hip_runtime.h>
#include <math.h>

#define N_NODES 100000

using bf16x8 = __attribute__((ext_vector_type(8))) short;
using f32x4  = __attribute__((ext_vector_type(4))) float;

static inline size_t align_up(size_t x, size_t a){ return (x + a - 1) & ~(a - 1); }

__device__ __forceinline__ unsigned short f2bf(float f){
  unsigned u = __float_as_uint(f);
  u = (u + 0x7fffu + ((u >> 16) & 1u)) >> 16;
  return (unsigned short)u;
}
__device__ __forceinline__ float bf2f(unsigned short h){
  return __uint_as_float(((unsigned)h) << 16);
}
__device__ __forceinline__ float bf_lo(unsigned u){ return __uint_as_float(u << 16); }
__device__ __forceinline__ float bf_hi(unsigned u){ return __uint_as_float(u & 0xffff0000u); }

// ---------------- zero ----------------
__global__ void k_zero(int* __restrict__ p, int n){
  int i = blockIdx.x*blockDim.x + threadIdx.x;
  if(i < n) p[i] = 0;
}

// ------- convert + count (padded counters, rank = atomic return) -------
__global__ void k_convert_count(const int* __restrict__ ei,
                                int* __restrict__ src32, int* __restrict__ dst32,
                                int* __restrict__ rank, int* __restrict__ cnt_p, int E){
  __shared__ int s_is64;
  if(threadIdx.x == 0){
    int is64 = 1;
    for(int k=0;k<64;k++){ if(ei[2*k+1] != 0){ is64 = 0; break; } }
    s_is64 = is64;
  }
  __syncthreads();
  int is64 = s_is64;
  int stride = gridDim.x * blockDim.x;
  for(int e = blockIdx.x*blockDim.x + threadIdx.x; e < E; e += stride){
    int s, d;
    if(is64){ s = ei[2*e]; d = ei[2*(E + e)]; }
    else    { s = ei[e];   d = ei[E + e]; }
    src32[e] = s; dst32[e] = d;
    rank[e] = atomicAdd(&cnt_p[(size_t)d*16], 1);   // one counter per 64B line
  }
}

// ---------------- scan over padded counters (3-phase) ----------------
__global__ void k_scan_part(const int* __restrict__ cnt_p, int* __restrict__ bsum, int n){
  __shared__ int red[256];
  int b = blockIdx.x, t = threadIdx.x;
  int base = b*1024 + t*4;
  int s = 0;
  #pragma unroll
  for(int k=0;k<4;k++){ int i = base + k; if(i < n) s += cnt_p[(size_t)i*16]; }
  red[t] = s; __syncthreads();
  for(int off=128; off>0; off>>=1){
    if(t < off) red[t] += red[t+off];
    __syncthreads();
  }
  if(t==0) bsum[b] = red[0];
}

__global__ void k_scan_top(int* __restrict__ bsum, int nb){
  __shared__ int sh[128];
  int t = threadIdx.x;
  int v = (t < nb) ? bsum[t] : 0;
  sh[t] = v; __syncthreads();
  int inc = v;
  for(int off=1; off<128; off<<=1){
    int add = (t >= off) ? sh[t-off] : 0;
    __syncthreads();
    inc += add; sh[t] = inc;
    __syncthreads();
  }
  if(t < nb) bsum[t] = inc - v;   // exclusive
}

__global__ void k_scan_down(const int* __restrict__ cnt_p, const int* __restrict__ bsum,
                            int* __restrict__ offs, float* __restrict__ dinv, int n, int E){
  __shared__ int sh[256];
  int b = blockIdx.x, t = threadIdx.x;
  int base = b*1024 + t*4;
  int c[4]; int local = 0;
  #pragma unroll
  for(int k=0;k<4;k++){ int i = base + k; c[k] = (i < n) ? cnt_p[(size_t)i*16] : 0; local += c[k]; }
  sh[t] = local; __syncthreads();
  int inc = local;
  for(int off=1; off<256; off<<=1){
    int add = (t >= off) ? sh[t-off] : 0;
    __syncthreads();
    inc += add; sh[t] = inc;
    __syncthreads();
  }
  int running = bsum[b] + (inc - local);
  #pragma unroll
  for(int k=0;k<4;k++){
    int i = base + k;
    if(i < n){
      offs[i] = running;
      dinv[i] = rsqrtf((float)(c[k] + 1));   // deg includes self-loop
      running += c[k];
    }
  }
  if(b==0 && t==0) offs[n] = E;
}

// ---------------- fill: no atomics (rank precomputed) ----------------
__global__ void k_fill(const int* __restrict__ src32, const int* __restrict__ dst32,
                       const int* __restrict__ rank, const int* __restrict__ offs,
                       int* __restrict__ csr, int E){
  int stride = gridDim.x * blockDim.x;
  for(int e = blockIdx.x*blockDim.x + threadIdx.x; e < E; e += stride){
    csr[offs[dst32[e]] + rank[e]] = src32[e];
  }
}

// ------- W1 -> fragment-ordered split-bf16 (hi/lo), K padded to 192 -------
// layout: shorts[ ((s*8 + t)*64 + lane)*16 + (0..7 hi | 8..15 lo) ]
__global__ void k_prep_w1(const float* __restrict__ w1, unsigned short* __restrict__ w1b){
  int id = blockIdx.x*blockDim.x + threadIdx.x;
  if(id >= 6*8*64) return;
  int lane = id & 63;
  int st = id >> 6;
  int s = st >> 3, t = st & 7;
  int g = lane >> 4;
  int nn = t*16 + (lane & 15);
  unsigned short* dst = w1b + (size_t)((s*8 + t)*64 + lane)*16;
  #pragma unroll
  for(int j=0;j<8;j++){
    int k = s*32 + g*8 + j;
    float v = (k < 165) ? w1[(size_t)k*128 + nn] : 0.f;
    unsigned short hi = f2bf(v);
    unsigned short lo = f2bf(v - bf2f(hi));
    dst[j] = hi; dst[8+j] = lo;
  }
}

// ------- GEMM via MFMA: hsc = bf16( (x @ W1) * dinv[row] ) -------
// block = 256 thr = 4 waves; wave computes 16 rows x 128 cols.
// Transposed-product trick: A-operand = W1 fragment (n = lane&15),
// B-operand = x fragment (m = lane&15)  =>  lane owns row m, cols g*4+r per tile.
__global__ __launch_bounds__(256) void k_gemm_mfma(const float* __restrict__ x,
                                                   const unsigned short* __restrict__ w1b,
                                                   const float* __restrict__ dinv,
                                                   unsigned short* __restrict__ hsc, int n){
  int lane = threadIdx.x & 63;
  int w    = threadIdx.x >> 6;
  int m    = lane & 15;
  int g    = lane >> 4;
  int row  = blockIdx.x*64 + w*16 + m;
  int rowc = row < n ? row : n-1;
  const float* xr = x + (size_t)rowc * 165;
  const bf16x8* wb = (const bf16x8*)w1b;

  f32x4 acc[8];
  #pragma unroll
  for(int t=0;t<8;t++){ acc[t][0]=0.f; acc[t][1]=0.f; acc[t][2]=0.f; acc[t][3]=0.f; }

  #pragma unroll
  for(int s=0;s<6;s++){
    int k0 = s*32 + g*8;
    float v[8];
    if(s < 5){
      #pragma unroll
      for(int j=0;j<8;j++) v[j] = xr[k0+j];
    }else{
      #pragma unroll
      for(int j=0;j<8;j++){ int k = k0+j; v[j] = (k < 165) ? xr[k] : 0.f; }
    }
    bf16x8 ah, al;
    #pragma unroll
    for(int j=0;j<8;j++){
      unsigned short hi = f2bf(v[j]);
      ah[j] = (short)hi;
      al[j] = (short)f2bf(v[j] - bf2f(hi));
    }
    #pragma unroll
    for(int t=0;t<8;t++){
      int bidx = ((s*8 + t)*64 + lane)*2;
      bf16x8 bh = wb[bidx];
      bf16x8 bl = wb[bidx + 1];
      acc[t] = __builtin_amdgcn_mfma_f32_16x16x32_bf16(bh, ah, acc[t], 0, 0, 0);
      acc[t] = __builtin_amdgcn_mfma_f32_16x16x32_bf16(bh, al, acc[t], 0, 0, 0);
      acc[t] = __builtin_amdgcn_mfma_f32_16x16x32_bf16(bl, ah, acc[t], 0, 0, 0);
    }
  }

  if(row < n){
    float di = dinv[row];
    unsigned* hp = (unsigned*)(hsc + (size_t)row*128);
    #pragma unroll
    for(int t=0;t<8;t++){
      unsigned short q0 = f2bf(acc[t][0]*di);
      unsigned short q1 = f2bf(acc[t][1]*di);
      unsigned short q2 = f2bf(acc[t][2]*di);
      unsigned short q3 = f2bf(acc[t][3]*di);
      int nbase = t*16 + g*4;              // 4 consecutive cols
      hp[(nbase>>1)    ] = (unsigned)q0 | ((unsigned)q1 << 16);
      hp[(nbase>>1) + 1] = (unsigned)q2 | ((unsigned)q3 << 16);
    }
  }
}

// ------- layer-1 aggregation + relu + dot(W4) fused; emits g = dinv*h2 -------
__global__ __launch_bounds__(256) void k_agg1(const unsigned short* __restrict__ hsc,
                                              const int* __restrict__ offs,
                                              const int* __restrict__ csr,
                                              const float* __restrict__ dinv,
                                              const float* __restrict__ b1,
                                              const float* __restrict__ w4,
                                              float* __restrict__ g, int n){
  int wv = threadIdx.x >> 6;
  int lane = threadIdx.x & 63;
  int i = blockIdx.x * 4 + wv;
  if(i >= n) return;

  float di = dinv[i];
  int s0 = offs[i], s1 = offs[i+1];
  int f = lane * 2;

  float ax = 0.f, ay = 0.f;
  int e = s0;
  for(; e + 1 < s1; e += 2){
    int sA = csr[e], sB = csr[e+1];
    unsigned uA = ((const unsigned*)(hsc + (size_t)sA*128))[lane];
    unsigned uB = ((const unsigned*)(hsc + (size_t)sB*128))[lane];
    ax += bf_lo(uA) + bf_lo(uB);
    ay += bf_hi(uA) + bf_hi(uB);
  }
  if(e < s1){
    unsigned uA = ((const unsigned*)(hsc + (size_t)csr[e]*128))[lane];
    ax += bf_lo(uA);
    ay += bf_hi(uA);
  }
  unsigned uS = ((const unsigned*)(hsc + (size_t)i*128))[lane];
  ax = di * (ax + bf_lo(uS));
  ay = di * (ay + bf_hi(uS));

  float2 bb = *(const float2*)&b1[f];
  float o0 = fmaxf(ax + bb.x, 0.f);
  float o1 = fmaxf(ay + bb.y, 0.f);

  float2 wv4 = *(const float2*)&w4[f];
  float p = o0*wv4.x + o1*wv4.y;
  #pragma unroll
  for(int offm=32; offm>0; offm>>=1) p += __shfl_xor(p, offm, 64);
  if(lane == 0) g[i] = di * p;     // g = dinv * h2
}

// ------- layer-2 aggregation via CSR gather + sigmoid (8 lanes/node) -------
__global__ void k_agg2c(const float* __restrict__ g, const int* __restrict__ offs,
                        const int* __restrict__ csr, const float* __restrict__ dinv,
                        const float* __restrict__ b4, float* __restrict__ out, int n){
  int lane = threadIdx.x & 63;
  int wv   = threadIdx.x >> 6;
  int sub  = lane & 7;
  int i = blockIdx.x*32 + wv*8 + (lane >> 3);
  if(i >= n) return;
  int s1 = offs[i+1];
  float p = 0.f;
  for(int e = offs[i] + sub; e < s1; e += 8) p += g[csr[e]];
  p += __shfl_xor(p, 4, 8);
  p += __shfl_xor(p, 2, 8);
  p += __shfl_xor(p, 1, 8);
  if(sub == 0){
    float di = dinv[i];
    float z = di*(p + g[i]) + b4[0];
    out[i] = 1.f/(1.f+expf(-z));
  }
}

// ---------------- launch ----------------
extern "C" void kernel_launch(void* const* d_in, const int* in_sizes, int n_in,
                              void* d_out, int out_size, void* d_ws, size_t ws_size,
                              hipStream_t stream){
  const float* x  = (const float*)d_in[0];
  const int*   ei = (const int*)d_in[1];
  const float* w1 = (const float*)d_in[2];
  const float* b1 = (const float*)d_in[3];
  const float* w4 = (const float*)d_in[4];
  const float* b4 = (const float*)d_in[5];
  float* out = (float*)d_out;

  const int n = N_NODES;
  const int E = in_sizes[1] / 2;

  char* ws = (char*)d_ws;
  size_t off = 0;
  auto carve = [&](size_t bytes)->void*{
    void* p = ws + off; off = align_up(off + bytes, 256); return p;
  };
  int*   cnt_p = (int*)carve((size_t)n*16*4);       // padded: 1 counter / 64B line
  int*   offs  = (int*)carve((size_t)(n+1)*4);
  int*   bsum  = (int*)carve(128*4);
  float* dinv  = (float*)carve((size_t)n*4);
  int*   src32 = (int*)carve((size_t)E*4);
  int*   dst32 = (int*)carve((size_t)E*4);
  int*   rank  = (int*)carve((size_t)E*4);
  int*   csr   = (int*)carve((size_t)E*4);
  unsigned short* w1b = (unsigned short*)carve((size_t)6*8*64*16*2);
  unsigned short* hsc = (unsigned short*)carve((size_t)n*128*2);
  float* g     = (float*)carve((size_t)n*4);
  (void)ws_size;

  int nb = (n + 1023) / 1024;   // 98

  k_zero         <<<(n*16+255)/256, 256, 0, stream>>>(cnt_p, n*16);
  k_convert_count<<<2048, 256, 0, stream>>>(ei, src32, dst32, rank, cnt_p, E);
  k_scan_part    <<<nb, 256, 0, stream>>>(cnt_p, bsum, n);
  k_scan_top     <<<1, 128, 0, stream>>>(bsum, nb);
  k_scan_down    <<<nb, 256, 0, stream>>>(cnt_p, bsum, offs, dinv, n, E);
  k_fill         <<<2048, 256, 0, stream>>>(src32, dst32, rank, offs, csr, E);
  k_prep_w1      <<<12, 256, 0, stream>>>(w1, w1b);
  k_gemm_mfma    <<<(n+63)/64, 256, 0, stream>>>(x, w1b, dinv, hsc, n);
  k_agg1         <<<(n+3)/4, 256, 0, stream>>>(hsc, offs, csr, dinv, b1, w4, g, n);
  k_agg2c        <<<(n+31)/32, 256, 0, stream>>>(g, offs, csr, dinv, b4, out, n);
}

// Round 5
// 350.872 us; speedup vs baseline: 1.6595x; 1.0845x over previous
//
#include <hip/hip_runtime.h>
#include <math.h>

#define N_NODES 100000

using bf16x8 = __attribute__((ext_vector_type(8))) short;
using f32x4  = __attribute__((ext_vector_type(4))) float;

static inline size_t align_up(size_t x, size_t a){ return (x + a - 1) & ~(a - 1); }

__device__ __forceinline__ unsigned short f2bf(float f){
  unsigned u = __float_as_uint(f);
  u = (u + 0x7fffu + ((u >> 16) & 1u)) >> 16;
  return (unsigned short)u;
}
__device__ __forceinline__ float bf2f(unsigned short h){
  return __uint_as_float(((unsigned)h) << 16);
}
__device__ __forceinline__ float bf_lo(unsigned u){ return __uint_as_float(u << 16); }
__device__ __forceinline__ float bf_hi(unsigned u){ return __uint_as_float(u & 0xffff0000u); }

// ---------------- zero ----------------
__global__ void k_zero(int* __restrict__ p, int n){
  int i = blockIdx.x*blockDim.x + threadIdx.x;
  if(i < n) p[i] = 0;
}

// ------- convert + count (padded counters, rank = atomic return) -------
__global__ void k_convert_count(const int* __restrict__ ei,
                                int* __restrict__ src32, int* __restrict__ dst32,
                                int* __restrict__ rank, int* __restrict__ cnt_p, int E){
  __shared__ int s_is64;
  if(threadIdx.x == 0){
    int is64 = 1;
    for(int k=0;k<64;k++){ if(ei[2*k+1] != 0){ is64 = 0; break; } }
    s_is64 = is64;
  }
  __syncthreads();
  int is64 = s_is64;
  int stride = gridDim.x * blockDim.x;
  for(int e = blockIdx.x*blockDim.x + threadIdx.x; e < E; e += stride){
    int s, d;
    if(is64){ s = ei[2*e]; d = ei[2*(E + e)]; }
    else    { s = ei[e];   d = ei[E + e]; }
    src32[e] = s; dst32[e] = d;
    rank[e] = atomicAdd(&cnt_p[(size_t)d*16], 1);   // one counter per 64B line
  }
}

// ---------------- scan over padded counters (3-phase) ----------------
__global__ void k_scan_part(const int* __restrict__ cnt_p, int* __restrict__ bsum, int n){
  __shared__ int red[256];
  int b = blockIdx.x, t = threadIdx.x;
  int base = b*1024 + t*4;
  int s = 0;
  #pragma unroll
  for(int k=0;k<4;k++){ int i = base + k; if(i < n) s += cnt_p[(size_t)i*16]; }
  red[t] = s; __syncthreads();
  for(int off=128; off>0; off>>=1){
    if(t < off) red[t] += red[t+off];
    __syncthreads();
  }
  if(t==0) bsum[b] = red[0];
}

__global__ void k_scan_top(int* __restrict__ bsum, int nb){
  __shared__ int sh[128];
  int t = threadIdx.x;
  int v = (t < nb) ? bsum[t] : 0;
  sh[t] = v; __syncthreads();
  int inc = v;
  for(int off=1; off<128; off<<=1){
    int add = (t >= off) ? sh[t-off] : 0;
    __syncthreads();
    inc += add; sh[t] = inc;
    __syncthreads();
  }
  if(t < nb) bsum[t] = inc - v;   // exclusive
}

__global__ void k_scan_down(const int* __restrict__ cnt_p, const int* __restrict__ bsum,
                            int* __restrict__ offs, float* __restrict__ dinv, int n, int E){
  __shared__ int sh[256];
  int b = blockIdx.x, t = threadIdx.x;
  int base = b*1024 + t*4;
  int c[4]; int local = 0;
  #pragma unroll
  for(int k=0;k<4;k++){ int i = base + k; c[k] = (i < n) ? cnt_p[(size_t)i*16] : 0; local += c[k]; }
  sh[t] = local; __syncthreads();
  int inc = local;
  for(int off=1; off<256; off<<=1){
    int add = (t >= off) ? sh[t-off] : 0;
    __syncthreads();
    inc += add; sh[t] = inc;
    __syncthreads();
  }
  int running = bsum[b] + (inc - local);
  #pragma unroll
  for(int k=0;k<4;k++){
    int i = base + k;
    if(i < n){
      offs[i] = running;
      dinv[i] = rsqrtf((float)(c[k] + 1));   // deg includes self-loop
      running += c[k];
    }
  }
  if(b==0 && t==0) offs[n] = E;
}

// ---------------- fill: no atomics (rank precomputed) ----------------
__global__ void k_fill(const int* __restrict__ src32, const int* __restrict__ dst32,
                       const int* __restrict__ rank, const int* __restrict__ offs,
                       int* __restrict__ csr, int E){
  int stride = gridDim.x * blockDim.x;
  for(int e = blockIdx.x*blockDim.x + threadIdx.x; e < E; e += stride){
    csr[offs[dst32[e]] + rank[e]] = src32[e];
  }
}

// ------- W1 -> fragment-ordered split-bf16 (hi/lo), K padded to 192 -------
__global__ void k_prep_w1(const float* __restrict__ w1, unsigned short* __restrict__ w1b){
  int id = blockIdx.x*blockDim.x + threadIdx.x;
  if(id >= 6*8*64) return;
  int lane = id & 63;
  int st = id >> 6;
  int s = st >> 3, t = st & 7;
  int g = lane >> 4;
  int nn = t*16 + (lane & 15);
  unsigned short* dst = w1b + (size_t)((s*8 + t)*64 + lane)*16;
  #pragma unroll
  for(int j=0;j<8;j++){
    int k = s*32 + g*8 + j;
    float v = (k < 165) ? w1[(size_t)k*128 + nn] : 0.f;
    unsigned short hi = f2bf(v);
    unsigned short lo = f2bf(v - bf2f(hi));
    dst[j] = hi; dst[8+j] = lo;
  }
}

// ------- GEMM via MFMA, x staged through LDS coalesced -------
// block = 256 thr = 4 waves; wave computes 16 rows x 128 cols.
__global__ __launch_bounds__(256) void k_gemm_mfma(const float* __restrict__ x,
                                                   const unsigned short* __restrict__ w1b,
                                                   const float* __restrict__ dinv,
                                                   unsigned short* __restrict__ hsc, int n){
  __shared__ float xs[64*172];           // row stride 172: b128-aligned, 2-way banks
  int t = threadIdx.x;
  int rowbase = blockIdx.x*64;
  int nrow = min(64, n - rowbase);
  int nfl = nrow * 165;
  const float* xblk = x + (size_t)rowbase*165;
  for(int f = t; f < nfl; f += 256){
    int r = f / 165;
    int c = f - r*165;
    xs[r*172 + c] = xblk[f];
  }
  __syncthreads();

  int lane = threadIdx.x & 63;
  int w    = threadIdx.x >> 6;
  int m    = lane & 15;
  int g    = lane >> 4;
  int row  = rowbase + w*16 + m;
  const float* xr = xs + (w*16 + m)*172;
  const bf16x8* wb = (const bf16x8*)w1b;

  f32x4 acc[8];
  #pragma unroll
  for(int q=0;q<8;q++){ acc[q][0]=0.f; acc[q][1]=0.f; acc[q][2]=0.f; acc[q][3]=0.f; }

  #pragma unroll
  for(int s=0;s<6;s++){
    int k0 = s*32 + g*8;
    float v[8];
    if(s < 5){
      #pragma unroll
      for(int j=0;j<8;j++) v[j] = xr[k0+j];
    }else{
      #pragma unroll
      for(int j=0;j<8;j++){ int k = k0+j; v[j] = (k < 165) ? xr[k] : 0.f; }
    }
    bf16x8 ah, al;
    #pragma unroll
    for(int j=0;j<8;j++){
      unsigned short hi = f2bf(v[j]);
      ah[j] = (short)hi;
      al[j] = (short)f2bf(v[j] - bf2f(hi));
    }
    #pragma unroll
    for(int q=0;q<8;q++){
      int bidx = ((s*8 + q)*64 + lane)*2;
      bf16x8 bh = wb[bidx];
      bf16x8 bl = wb[bidx + 1];
      acc[q] = __builtin_amdgcn_mfma_f32_16x16x32_bf16(bh, ah, acc[q], 0, 0, 0);
      acc[q] = __builtin_amdgcn_mfma_f32_16x16x32_bf16(bh, al, acc[q], 0, 0, 0);
      acc[q] = __builtin_amdgcn_mfma_f32_16x16x32_bf16(bl, ah, acc[q], 0, 0, 0);
    }
  }

  if(row < n){
    float di = dinv[row];
    unsigned* hp = (unsigned*)(hsc + (size_t)row*128);
    #pragma unroll
    for(int q=0;q<8;q++){
      unsigned short q0 = f2bf(acc[q][0]*di);
      unsigned short q1 = f2bf(acc[q][1]*di);
      unsigned short q2 = f2bf(acc[q][2]*di);
      unsigned short q3 = f2bf(acc[q][3]*di);
      int nbase = q*16 + g*4;
      hp[(nbase>>1)    ] = (unsigned)q0 | ((unsigned)q1 << 16);
      hp[(nbase>>1) + 1] = (unsigned)q2 | ((unsigned)q3 << 16);
    }
  }
}

// ------- layer-1 aggregation + relu + dot(W4) fused; emits g = dinv*h2 -------
// wave per node; half-wave per edge (2 edges/iter), dwordx2/lane, unroll x2
__global__ __launch_bounds__(256) void k_agg1(const unsigned short* __restrict__ hsc,
                                              const int* __restrict__ offs,
                                              const int* __restrict__ csr,
                                              const float* __restrict__ dinv,
                                              const float* __restrict__ b1,
                                              const float* __restrict__ w4,
                                              float* __restrict__ g, int n){
  int wv = threadIdx.x >> 6;
  int lane = threadIdx.x & 63;
  int half = lane >> 5;
  int sub  = lane & 31;
  int i = blockIdx.x * 4 + wv;
  if(i >= n) return;

  float di = dinv[i];
  int s0 = offs[i], s1 = offs[i+1];
  const unsigned* base = (const unsigned*)hsc;   // row = 64 dwords

  float a0=0.f, a1=0.f, a2=0.f, a3=0.f;
  int e = s0 + half;
  for(; e + 2 < s1; e += 4){
    int sA = csr[e], sB = csr[e+2];
    uint2 uA = *(const uint2*)(base + (size_t)sA*64 + sub*2);
    uint2 uB = *(const uint2*)(base + (size_t)sB*64 + sub*2);
    a0 += bf_lo(uA.x) + bf_lo(uB.x);
    a1 += bf_hi(uA.x) + bf_hi(uB.x);
    a2 += bf_lo(uA.y) + bf_lo(uB.y);
    a3 += bf_hi(uA.y) + bf_hi(uB.y);
  }
  if(e < s1){
    int sA = csr[e];
    uint2 uA = *(const uint2*)(base + (size_t)sA*64 + sub*2);
    a0 += bf_lo(uA.x); a1 += bf_hi(uA.x);
    a2 += bf_lo(uA.y); a3 += bf_hi(uA.y);
  }
  if(half == 0){   // self-loop once
    uint2 uS = *(const uint2*)(base + (size_t)i*64 + sub*2);
    a0 += bf_lo(uS.x); a1 += bf_hi(uS.x);
    a2 += bf_lo(uS.y); a3 += bf_hi(uS.y);
  }
  a0 += __shfl_xor(a0, 32, 64);
  a1 += __shfl_xor(a1, 32, 64);
  a2 += __shfl_xor(a2, 32, 64);
  a3 += __shfl_xor(a3, 32, 64);

  int f = sub*4;
  float4 bb  = *(const float4*)&b1[f];
  float4 wv4 = *(const float4*)&w4[f];
  float o0 = fmaxf(di*a0 + bb.x, 0.f);
  float o1 = fmaxf(di*a1 + bb.y, 0.f);
  float o2 = fmaxf(di*a2 + bb.z, 0.f);
  float o3 = fmaxf(di*a3 + bb.w, 0.f);
  float p = o0*wv4.x + o1*wv4.y + o2*wv4.z + o3*wv4.w;
  #pragma unroll
  for(int offm=16; offm>0; offm>>=1) p += __shfl_xor(p, offm, 64);
  if(lane == 0) g[i] = di * p;     // g = dinv * h2
}

// ------- layer-2 aggregation via CSR gather + sigmoid (8 lanes/node) -------
__global__ void k_agg2c(const float* __restrict__ g, const int* __restrict__ offs,
                        const int* __restrict__ csr, const float* __restrict__ dinv,
                        const float* __restrict__ b4, float* __restrict__ out, int n){
  int lane = threadIdx.x & 63;
  int wv   = threadIdx.x >> 6;
  int sub  = lane & 7;
  int i = blockIdx.x*32 + wv*8 + (lane >> 3);
  if(i >= n) return;
  int s1 = offs[i+1];
  float p = 0.f;
  for(int e = offs[i] + sub; e < s1; e += 8) p += g[csr[e]];
  p += __shfl_xor(p, 4, 8);
  p += __shfl_xor(p, 2, 8);
  p += __shfl_xor(p, 1, 8);
  if(sub == 0){
    float di = dinv[i];
    float z = di*(p + g[i]) + b4[0];
    out[i] = 1.f/(1.f+expf(-z));
  }
}

// ---------------- launch ----------------
extern "C" void kernel_launch(void* const* d_in, const int* in_sizes, int n_in,
                              void* d_out, int out_size, void* d_ws, size_t ws_size,
                              hipStream_t stream){
  const float* x  = (const float*)d_in[0];
  const int*   ei = (const int*)d_in[1];
  const float* w1 = (const float*)d_in[2];
  const float* b1 = (const float*)d_in[3];
  const float* w4 = (const float*)d_in[4];
  const float* b4 = (const float*)d_in[5];
  float* out = (float*)d_out;

  const int n = N_NODES;
  const int E = in_sizes[1] / 2;

  char* ws = (char*)d_ws;
  size_t off = 0;
  auto carve = [&](size_t bytes)->void*{
    void* p = ws + off; off = align_up(off + bytes, 256); return p;
  };
  int*   cnt_p = (int*)carve((size_t)n*16*4);       // padded: 1 counter / 64B line
  int*   offs  = (int*)carve((size_t)(n+1)*4);
  int*   bsum  = (int*)carve(128*4);
  float* dinv  = (float*)carve((size_t)n*4);
  int*   src32 = (int*)carve((size_t)E*4);
  int*   dst32 = (int*)carve((size_t)E*4);
  int*   rank  = (int*)carve((size_t)E*4);
  int*   csr   = (int*)carve((size_t)E*4);
  unsigned short* w1b = (unsigned short*)carve((size_t)6*8*64*16*2);
  unsigned short* hsc = (unsigned short*)carve((size_t)n*128*2);
  float* g     = (float*)carve((size_t)n*4);
  (void)ws_size;

  int nb = (n + 1023) / 1024;   // 98

  k_zero         <<<(n*16+255)/256, 256, 0, stream>>>(cnt_p, n*16);
  k_convert_count<<<2048, 256, 0, stream>>>(ei, src32, dst32, rank, cnt_p, E);
  k_scan_part    <<<nb, 256, 0, stream>>>(cnt_p, bsum, n);
  k_scan_top     <<<1, 128, 0, stream>>>(bsum, nb);
  k_scan_down    <<<nb, 256, 0, stream>>>(cnt_p, bsum, offs, dinv, n, E);
  k_fill         <<<2048, 256, 0, stream>>>(src32, dst32, rank, offs, csr, E);
  k_prep_w1      <<<12, 256, 0, stream>>>(w1, w1b);
  k_gemm_mfma    <<<(n+63)/64, 256, 0, stream>>>(x, w1b, dinv, hsc, n);
  k_agg1         <<<(n+3)/4, 256, 0, stream>>>(hsc, offs, csr, dinv, b1, w4, g, n);
  k_agg2c        <<<(n+31)/32, 256, 0, stream>>>(g, offs, csr, dinv, b4, out, n);
}

// Round 8
// 323.115 us; speedup vs baseline: 1.8021x; 1.0859x over previous
//
#include <hip/hip_runtime.h>
#include <math.h>

#define N_NODES 100000

using bf16x8 = __attribute__((ext_vector_type(8))) short;
using f32x4  = __attribute__((ext_vector_type(4))) float;

static inline size_t align_up(size_t x, size_t a){ return (x + a - 1) & ~(a - 1); }

__device__ __forceinline__ unsigned short f2bf(float f){
  unsigned u = __float_as_uint(f);
  u = (u + 0x7fffu + ((u >> 16) & 1u)) >> 16;
  return (unsigned short)u;
}
__device__ __forceinline__ float bf2f(unsigned short h){
  return __uint_as_float(((unsigned)h) << 16);
}
__device__ __forceinline__ float bf_lo(unsigned u){ return __uint_as_float(u << 16); }
__device__ __forceinline__ float bf_hi(unsigned u){ return __uint_as_float(u & 0xffff0000u); }

__device__ __forceinline__ int xcd_id(){
  int x;
  asm volatile("s_getreg_b32 %0, hwreg(HW_REG_XCC_ID)" : "=s"(x));
  return x & 7;
}

// ---------------- zero ----------------
__global__ void k_zero(int* __restrict__ p, int n){
  int i = blockIdx.x*blockDim.x + threadIdx.x;
  if(i < n) p[i] = 0;
}

// ------- count into per-XCD replica; rank = (local_rank<<3)|xcd -------
__global__ void k_convert_count(const int* __restrict__ ei,
                                int* __restrict__ rank, int* __restrict__ cnt8,
                                int E, int n){
  __shared__ int s_is64;
  if(threadIdx.x == 0){
    int is64 = 1;
    for(int k=0;k<64;k++){ if(ei[2*k+1] != 0){ is64 = 0; break; } }
    s_is64 = is64;
  }
  __syncthreads();
  int is64 = s_is64;
  int r = xcd_id();
  int* my = cnt8 + (size_t)r * n;       // replica private to this XCD's L2
  int stride = gridDim.x * blockDim.x;
  for(int e = blockIdx.x*blockDim.x + threadIdx.x; e < E; e += stride){
    int d = is64 ? ei[2*(E + e)] : ei[E + e];
    int local = atomicAdd(&my[d], 1);
    rank[e] = (local << 3) | r;
  }
}

// ---------------- scan (3-phase) over 8 replicas ----------------
__global__ void k_scan_part(const int* __restrict__ cnt8, int* __restrict__ bsum, int n){
  __shared__ int red[256];
  int b = blockIdx.x, t = threadIdx.x;
  int base = b*1024 + t*4;
  int s = 0;
  #pragma unroll
  for(int k=0;k<4;k++){
    int i = base + k;
    if(i < n){
      #pragma unroll
      for(int r=0;r<8;r++) s += cnt8[(size_t)r*n + i];
    }
  }
  red[t] = s; __syncthreads();
  for(int off=128; off>0; off>>=1){
    if(t < off) red[t] += red[t+off];
    __syncthreads();
  }
  if(t==0) bsum[b] = red[0];
}

__global__ void k_scan_top(int* __restrict__ bsum, int nb){
  __shared__ int sh[128];
  int t = threadIdx.x;
  int v = (t < nb) ? bsum[t] : 0;
  sh[t] = v; __syncthreads();
  int inc = v;
  for(int off=1; off<128; off<<=1){
    int add = (t >= off) ? sh[t-off] : 0;
    __syncthreads();
    inc += add; sh[t] = inc;
    __syncthreads();
  }
  if(t < nb) bsum[t] = inc - v;   // exclusive
}

// overwrites cnt8[r][i] with global base offset for (i, replica r)
__global__ void k_scan_down(int* __restrict__ cnt8, const int* __restrict__ bsum,
                            int* __restrict__ offs, float* __restrict__ dinv, int n, int E){
  __shared__ int sh[256];
  int b = blockIdx.x, t = threadIdx.x;
  int base = b*1024 + t*4;
  int tot[4]; int local = 0;
  #pragma unroll
  for(int k=0;k<4;k++){
    int i = base + k; int s = 0;
    if(i < n){
      #pragma unroll
      for(int r=0;r<8;r++) s += cnt8[(size_t)r*n + i];
    }
    tot[k] = s; local += s;
  }
  sh[t] = local; __syncthreads();
  int inc = local;
  for(int off=1; off<256; off<<=1){
    int add = (t >= off) ? sh[t-off] : 0;
    __syncthreads();
    inc += add; sh[t] = inc;
    __syncthreads();
  }
  int running = bsum[b] + (inc - local);
  #pragma unroll
  for(int k=0;k<4;k++){
    int i = base + k;
    if(i < n){
      offs[i] = running;
      dinv[i] = rsqrtf((float)(tot[k] + 1));   // deg includes self-loop
      int acc = running;
      #pragma unroll
      for(int r=0;r<8;r++){
        int c = cnt8[(size_t)r*n + i];
        cnt8[(size_t)r*n + i] = acc;
        acc += c;
      }
      running += tot[k];
    }
  }
  if(b==0 && t==0) offs[n] = E;
}

// ---------------- fill: no atomics; reads ei directly ----------------
__global__ void k_fill(const int* __restrict__ ei, const int* __restrict__ rank,
                       const int* __restrict__ cbase, int* __restrict__ csr, int E, int n){
  __shared__ int s_is64;
  if(threadIdx.x == 0){
    int is64 = 1;
    for(int k=0;k<64;k++){ if(ei[2*k+1] != 0){ is64 = 0; break; } }
    s_is64 = is64;
  }
  __syncthreads();
  int is64 = s_is64;
  int stride = gridDim.x * blockDim.x;
  for(int e = blockIdx.x*blockDim.x + threadIdx.x; e < E; e += stride){
    int s, d;
    if(is64){ s = ei[2*e]; d = ei[2*(E + e)]; }
    else    { s = ei[e];   d = ei[E + e]; }
    int rk = rank[e];
    csr[cbase[(size_t)(rk & 7)*n + d] + (rk >> 3)] = s;
  }
}

// ------- W1 -> fragment-ordered split-bf16 (hi/lo), K padded to 192 -------
__global__ void k_prep_w1(const float* __restrict__ w1, unsigned short* __restrict__ w1b){
  int id = blockIdx.x*blockDim.x + threadIdx.x;
  if(id >= 6*8*64) return;
  int lane = id & 63;
  int st = id >> 6;
  int s = st >> 3, t = st & 7;
  int g = lane >> 4;
  int nn = t*16 + (lane & 15);
  unsigned short* dst = w1b + (size_t)((s*8 + t)*64 + lane)*16;
  #pragma unroll
  for(int j=0;j<8;j++){
    int k = s*32 + g*8 + j;
    float v = (k < 165) ? w1[(size_t)k*128 + nn] : 0.f;
    unsigned short hi = f2bf(v);
    unsigned short lo = f2bf(v - bf2f(hi));
    dst[j] = hi; dst[8+j] = lo;
  }
}

// ------- GEMM via MFMA, x staged through LDS coalesced -------
__global__ __launch_bounds__(256) void k_gemm_mfma(const float* __restrict__ x,
                                                   const unsigned short* __restrict__ w1b,
                                                   const float* __restrict__ dinv,
                                                   unsigned short* __restrict__ hsc, int n){
  __shared__ float xs[64*172];
  int t = threadIdx.x;
  int rowbase = blockIdx.x*64;
  int nrow = min(64, n - rowbase);
  int nfl = nrow * 165;
  const float* xblk = x + (size_t)rowbase*165;
  for(int f = t; f < nfl; f += 256){
    int r = f / 165;
    int c = f - r*165;
    xs[r*172 + c] = xblk[f];
  }
  __syncthreads();

  int lane = threadIdx.x & 63;
  int w    = threadIdx.x >> 6;
  int m    = lane & 15;
  int g    = lane >> 4;
  int row  = rowbase + w*16 + m;
  const float* xr = xs + (w*16 + m)*172;
  const bf16x8* wb = (const bf16x8*)w1b;

  f32x4 acc[8];
  #pragma unroll
  for(int q=0;q<8;q++){ acc[q][0]=0.f; acc[q][1]=0.f; acc[q][2]=0.f; acc[q][3]=0.f; }

  #pragma unroll
  for(int s=0;s<6;s++){
    int k0 = s*32 + g*8;
    float v[8];
    if(s < 5){
      #pragma unroll
      for(int j=0;j<8;j++) v[j] = xr[k0+j];
    }else{
      #pragma unroll
      for(int j=0;j<8;j++){ int k = k0+j; v[j] = (k < 165) ? xr[k] : 0.f; }
    }
    bf16x8 ah, al;
    #pragma unroll
    for(int j=0;j<8;j++){
      unsigned short hi = f2bf(v[j]);
      ah[j] = (short)hi;
      al[j] = (short)f2bf(v[j] - bf2f(hi));
    }
    #pragma unroll
    for(int q=0;q<8;q++){
      int bidx = ((s*8 + q)*64 + lane)*2;
      bf16x8 bh = wb[bidx];
      bf16x8 bl = wb[bidx + 1];
      acc[q] = __builtin_amdgcn_mfma_f32_16x16x32_bf16(bh, ah, acc[q], 0, 0, 0);
      acc[q] = __builtin_amdgcn_mfma_f32_16x16x32_bf16(bh, al, acc[q], 0, 0, 0);
      acc[q] = __builtin_amdgcn_mfma_f32_16x16x32_bf16(bl, ah, acc[q], 0, 0, 0);
    }
  }

  if(row < n){
    float di = dinv[row];
    unsigned* hp = (unsigned*)(hsc + (size_t)row*128);
    #pragma unroll
    for(int q=0;q<8;q++){
      unsigned short q0 = f2bf(acc[q][0]*di);
      unsigned short q1 = f2bf(acc[q][1]*di);
      unsigned short q2 = f2bf(acc[q][2]*di);
      unsigned short q3 = f2bf(acc[q][3]*di);
      int nbase = q*16 + g*4;
      hp[(nbase>>1)    ] = (unsigned)q0 | ((unsigned)q1 << 16);
      hp[(nbase>>1) + 1] = (unsigned)q2 | ((unsigned)q3 << 16);
    }
  }
}

// ------- layer-1 aggregation + relu + dot(W4) fused; emits g = dinv*h2 -------
// wave per node; quarter-wave (16 lanes x uint4 = 256B row) per edge, unroll x2
// => 8 independent row-gathers in flight per wave
__global__ __launch_bounds__(256) void k_agg1(const unsigned short* __restrict__ hsc,
                                              const int* __restrict__ offs,
                                              const int* __restrict__ csr,
                                              const float* __restrict__ dinv,
                                              const float* __restrict__ b1,
                                              const float* __restrict__ w4,
                                              float* __restrict__ g, int n){
  int wv = threadIdx.x >> 6;
  int lane = threadIdx.x & 63;
  int q   = lane >> 4;
  int sub = lane & 15;
  int i = blockIdx.x * 4 + wv;
  if(i >= n) return;

  float di = dinv[i];
  int s0 = offs[i], s1 = offs[i+1];
  const uint4* base = (const uint4*)hsc;   // row = 16 uint4

  float a0=0.f,a1=0.f,a2=0.f,a3=0.f,a4=0.f,a5=0.f,a6=0.f,a7=0.f;
  int e = s0 + q;
  for(; e + 4 < s1; e += 8){
    uint4 uA = base[(size_t)csr[e]*16 + sub];
    uint4 uB = base[(size_t)csr[e+4]*16 + sub];
    a0 += bf_lo(uA.x) + bf_lo(uB.x);  a1 += bf_hi(uA.x) + bf_hi(uB.x);
    a2 += bf_lo(uA.y) + bf_lo(uB.y);  a3 += bf_hi(uA.y) + bf_hi(uB.y);
    a4 += bf_lo(uA.z) + bf_lo(uB.z);  a5 += bf_hi(uA.z) + bf_hi(uB.z);
    a6 += bf_lo(uA.w) + bf_lo(uB.w);  a7 += bf_hi(uA.w) + bf_hi(uB.w);
  }
  if(e < s1){
    uint4 uA = base[(size_t)csr[e]*16 + sub];
    a0 += bf_lo(uA.x);  a1 += bf_hi(uA.x);
    a2 += bf_lo(uA.y);  a3 += bf_hi(uA.y);
    a4 += bf_lo(uA.z);  a5 += bf_hi(uA.z);
    a6 += bf_lo(uA.w);  a7 += bf_hi(uA.w);
  }
  if(q == 0){   // self-loop once
    uint4 uS = base[(size_t)i*16 + sub];
    a0 += bf_lo(uS.x);  a1 += bf_hi(uS.x);
    a2 += bf_lo(uS.y);  a3 += bf_hi(uS.y);
    a4 += bf_lo(uS.z);  a5 += bf_hi(uS.z);
    a6 += bf_lo(uS.w);  a7 += bf_hi(uS.w);
  }
  // combine quarters
  a0 += __shfl_xor(a0,16,64); a0 += __shfl_xor(a0,32,64);
  a1 += __shfl_xor(a1,16,64); a1 += __shfl_xor(a1,32,64);
  a2 += __shfl_xor(a2,16,64); a2 += __shfl_xor(a2,32,64);
  a3 += __shfl_xor(a3,16,64); a3 += __shfl_xor(a3,32,64);
  a4 += __shfl_xor(a4,16,64); a4 += __shfl_xor(a4,32,64);
  a5 += __shfl_xor(a5,16,64); a5 += __shfl_xor(a5,32,64);
  a6 += __shfl_xor(a6,16,64); a6 += __shfl_xor(a6,32,64);
  a7 += __shfl_xor(a7,16,64); a7 += __shfl_xor(a7,32,64);

  int f = sub*8;
  float4 bL = *(const float4*)&b1[f];
  float4 bH = *(const float4*)&b1[f+4];
  float4 wL = *(const float4*)&w4[f];
  float4 wH = *(const float4*)&w4[f+4];
  float p = fmaxf(di*a0 + bL.x, 0.f)*wL.x
          + fmaxf(di*a1 + bL.y, 0.f)*wL.y
          + fmaxf(di*a2 + bL.z, 0.f)*wL.z
          + fmaxf(di*a3 + bL.w, 0.f)*wL.w
          + fmaxf(di*a4 + bH.x, 0.f)*wH.x
          + fmaxf(di*a5 + bH.y, 0.f)*wH.y
          + fmaxf(di*a6 + bH.z, 0.f)*wH.z
          + fmaxf(di*a7 + bH.w, 0.f)*wH.w;
  p += __shfl_xor(p, 1, 64);
  p += __shfl_xor(p, 2, 64);
  p += __shfl_xor(p, 4, 64);
  p += __shfl_xor(p, 8, 64);
  if(lane == 0) g[i] = di * p;     // g = dinv * h2
}

// ------- layer-2 aggregation via CSR gather + sigmoid (8 lanes/node) -------
__global__ void k_agg2c(const float* __restrict__ g, const int* __restrict__ offs,
                        const int* __restrict__ csr, const float* __restrict__ dinv,
                        const float* __restrict__ b4, float* __restrict__ out, int n){
  int lane = threadIdx.x & 63;
  int wv   = threadIdx.x >> 6;
  int sub  = lane & 7;
  int i = blockIdx.x*32 + wv*8 + (lane >> 3);
  if(i >= n) return;
  int s1 = offs[i+1];
  float p = 0.f;
  for(int e = offs[i] + sub; e < s1; e += 8) p += g[csr[e]];
  p += __shfl_xor(p, 4, 8);
  p += __shfl_xor(p, 2, 8);
  p += __shfl_xor(p, 1, 8);
  if(sub == 0){
    float di = dinv[i];
    float z = di*(p + g[i]) + b4[0];
    out[i] = 1.f/(1.f+expf(-z));
  }
}

// ---------------- launch ----------------
extern "C" void kernel_launch(void* const* d_in, const int* in_sizes, int n_in,
                              void* d_out, int out_size, void* d_ws, size_t ws_size,
                              hipStream_t stream){
  const float* x  = (const float*)d_in[0];
  const int*   ei = (const int*)d_in[1];
  const float* w1 = (const float*)d_in[2];
  const float* b1 = (const float*)d_in[3];
  const float* w4 = (const float*)d_in[4];
  const float* b4 = (const float*)d_in[5];
  float* out = (float*)d_out;

  const int n = N_NODES;
  const int E = in_sizes[1] / 2;

  char* ws = (char*)d_ws;
  size_t off = 0;
  auto carve = [&](size_t bytes)->void*{
    void* p = ws + off; off = align_up(off + bytes, 256); return p;
  };
  int*   cnt8 = (int*)carve((size_t)8*n*4);     // per-XCD replicas, replica-major
  int*   offs = (int*)carve((size_t)(n+1)*4);
  int*   bsum = (int*)carve(128*4);
  float* dinv = (float*)carve((size_t)n*4);
  int*   rank = (int*)carve((size_t)E*4);
  int*   csr  = (int*)carve((size_t)E*4);
  unsigned short* w1b = (unsigned short*)carve((size_t)6*8*64*16*2);
  unsigned short* hsc = (unsigned short*)carve((size_t)n*128*2);
  float* g    = (float*)carve((size_t)n*4);
  (void)ws_size;

  int nb = (n + 1023) / 1024;   // 98

  k_zero         <<<(8*n+255)/256, 256, 0, stream>>>(cnt8, 8*n);
  k_convert_count<<<2048, 256, 0, stream>>>(ei, rank, cnt8, E, n);
  k_scan_part    <<<nb, 256, 0, stream>>>(cnt8, bsum, n);
  k_scan_top     <<<1, 128, 0, stream>>>(bsum, nb);
  k_scan_down    <<<nb, 256, 0, stream>>>(cnt8, bsum, offs, dinv, n, E);
  k_fill         <<<2048, 256, 0, stream>>>(ei, rank, cnt8, csr, E, n);
  k_prep_w1      <<<12, 256, 0, stream>>>(w1, w1b);
  k_gemm_mfma    <<<(n+63)/64, 256, 0, stream>>>(x, w1b, dinv, hsc, n);
  k_agg1         <<<(n+3)/4, 256, 0, stream>>>(hsc, offs, csr, dinv, b1, w4, g, n);
  k_agg2c        <<<(n+31)/32, 256, 0, stream>>>(g, offs, csr, dinv, b4, out, n);
}